// Round 1
// baseline (327.348 us; speedup 1.0000x reference)
//
#include <hip/hip_runtime.h>
#include <hip/hip_bf16.h>
#include <math.h>

// Problem constants
#define N_   64
#define T_   1000
#define E_   512
#define A_   256
#define O_   80
#define S_   64
#define H_   1024
#define G4_  4096
#define KC_  31   // conv kernel size, K//2 = 15

__device__ __forceinline__ float sigmoidf_(float x) { return 1.f / (1.f + __expf(-x)); }
__device__ __forceinline__ float softsignf_(float x) { return x / (1.f + fabsf(x)); }

// ---------------------------------------------------------------------------
// K1a: attention logits, partial per a-quadrant.
// grid (64, 4) blocks x 256 threads. Block (n, aq): a = aq*64 + lane.
// Wave w handles timesteps {w, w+4, w+8(if<10)}.
// part[(n*10+t)*4 + aq] = sum_a tanh(e[n,t,a]) * w_proj[a]   (over this aq's 64 a)
// ---------------------------------------------------------------------------
__global__ void logits_kernel(const float* __restrict__ enc,
                              const float* __restrict__ spkr,
                              const float* __restrict__ w_enc,
                              const float* __restrict__ b_enc,
                              const float* __restrict__ w_spkr,
                              const float* __restrict__ conv_w,
                              const float* __restrict__ w_proj,
                              float* __restrict__ part) {
  int n  = blockIdx.x;
  int aq = blockIdx.y;
  int tid = threadIdx.x;
  int al = tid & 63;      // lane = local a
  int tg = tid >> 6;      // wave index = timestep group
  int a  = aq * 64 + al;

  __shared__ float er[10][E_];   // 20 KB: enc rows t=0..9
  __shared__ float sp[S_];

  if (tid < S_) sp[tid] = spkr[n * S_ + tid];
  for (int idx = tid; idx < 10 * E_; idx += 256) {
    er[idx >> 9][idx & 511] = enc[(size_t)n * T_ * E_ + idx];
  }
  __syncthreads();

  // bias_spkr for this a
  float bs = 0.f;
  for (int s = 0; s < S_; ++s) bs += sp[s] * w_spkr[s * A_ + a];
  bs = softsignf_(bs);

  int t0 = tg, t1 = tg + 4;
  int has2 = (tg < 2);
  int t2 = has2 ? tg + 8 : 0;

  float be = b_enc[a];
  float acc0 = be, acc1 = be, acc2 = be;
  for (int k = 0; k < E_; ++k) {
    float we = w_enc[k * A_ + a];
    acc0 = fmaf(er[t0][k], we, acc0);
    acc1 = fmaf(er[t1][k], we, acc1);
    acc2 = fmaf(er[t2][k], we, acc2);
  }

  float wp = w_proj[a];
  float e0 = softsignf_(acc0) + bs + conv_w[a * KC_ + (15 - t0)];
  float e1 = softsignf_(acc1) + bs + conv_w[a * KC_ + (15 - t1)];
  float e2 = softsignf_(acc2) + bs + conv_w[a * KC_ + (15 - t2)];
  float l0 = tanhf(e0) * wp;
  float l1 = tanhf(e1) * wp;
  float l2 = tanhf(e2) * wp;

  // wave-level 64-lane reduction
  #pragma unroll
  for (int off = 32; off > 0; off >>= 1) {
    l0 += __shfl_down(l0, off);
    l1 += __shfl_down(l1, off);
    l2 += __shfl_down(l2, off);
  }
  if (al == 0) {
    part[(n * 10 + t0) * 4 + aq] = l0;
    part[(n * 10 + t1) * 4 + aq] = l1;
    if (has2) part[(n * 10 + t2) * 4 + aq] = l2;
  }
}

// ---------------------------------------------------------------------------
// K1b: softmax (10 wide) + context + prenet + assemble x = [pre2|ctx|spkr].
// grid 64 blocks (one per n) x 256 threads.
// ---------------------------------------------------------------------------
__global__ void ctx_prenet_kernel(const float* __restrict__ enc,
                                  const float* __restrict__ dec_in,
                                  const float* __restrict__ spkr,
                                  const int*   __restrict__ lengths,
                                  const float* __restrict__ part,
                                  const float* __restrict__ w_p1,
                                  const float* __restrict__ b_p1,
                                  const float* __restrict__ w_p2,
                                  const float* __restrict__ b_p2,
                                  float* __restrict__ xbuf) {
  int n = blockIdx.x;
  int tid = threadIdx.x;
  __shared__ float att[10];
  __shared__ float incat[O_ + S_];   // 144
  __shared__ float pre1[512];
  __shared__ float sp[S_];

  if (tid < S_) { sp[tid] = spkr[n * S_ + tid]; incat[O_ + tid] = sp[tid]; }
  if (tid < O_) incat[tid] = dec_in[n * O_ + tid];
  if (tid == 0) {
    int lim = lengths[n] - 1; if (lim < 0) lim = 0;
    int tmax = lim < 9 ? lim : 9;
    float lg[10];
    float m = -1e30f;
    for (int t = 0; t <= tmax; ++t) {
      const float* p = &part[(n * 10 + t) * 4];
      lg[t] = p[0] + p[1] + p[2] + p[3];
      m = fmaxf(m, lg[t]);
    }
    float ssum = 0.f;
    for (int t = 0; t <= tmax; ++t) { float w = __expf(lg[t] - m); att[t] = w; ssum += w; }
    float inv = 1.f / fmaxf(ssum, 1e-12f);
    for (int t = 0; t <= tmax; ++t) att[t] *= inv;
    for (int t = tmax + 1; t < 10; ++t) att[t] = 0.f;
  }
  __syncthreads();

  // context -> xbuf[n][256 + e]
  for (int e = tid; e < E_; e += 256) {
    float c = 0.f;
    #pragma unroll
    for (int t = 0; t < 10; ++t)
      c = fmaf(att[t], enc[(size_t)n * T_ * E_ + t * E_ + e], c);
    xbuf[n * 832 + 256 + e] = c;
  }
  if (tid < S_) xbuf[n * 832 + 768 + tid] = sp[tid];

  // pre1 = relu(incat @ w_p1 + b_p1)   (144 x 512)
  for (int c = tid; c < 512; c += 256) {
    float v = b_p1[c];
    for (int k = 0; k < O_ + S_; ++k) v = fmaf(incat[k], w_p1[k * 512 + c], v);
    pre1[c] = fmaxf(v, 0.f);
  }
  __syncthreads();

  // pre2 = relu(pre1 @ w_p2 + b_p2)    (512 x 256) -> xbuf[n][0..255]
  {
    float v = b_p2[tid];
    for (int k = 0; k < 512; ++k) v = fmaf(pre1[k], w_p2[k * A_ + tid], v);
    xbuf[n * 832 + tid] = fmaxf(v, 0.f);
  }
}

// ---------------------------------------------------------------------------
// GEMM: G[64 x 4096] = X[64 x K] @ W[K x 4096] + b1 + b2, only i/g/o columns.
// grid 192 blocks (16-col tiles over the 3072 live cols) x 256 threads.
// Thread (tr,tc) computes rows tr*4..tr*4+3, col c0+tc.
// ---------------------------------------------------------------------------
__global__ void gemm_gates_kernel(const float* __restrict__ X, int ldx, int K,
                                  const float* __restrict__ W,
                                  const float* __restrict__ b1,
                                  const float* __restrict__ b2,
                                  float* __restrict__ G) {
  int bt = blockIdx.x;
  int c0 = bt * 16; if (c0 >= 1024) c0 += 1024;   // skip dead f-gate columns
  int tid = threadIdx.x;
  int tr = tid >> 4;     // 0..15
  int tc = tid & 15;     // 0..15

  __shared__ __align__(16) float xs[32][64];
  __shared__ __align__(16) float wst[16][36];     // padded stride kills bank conflicts

  float acc0 = 0.f, acc1 = 0.f, acc2 = 0.f, acc3 = 0.f;

  for (int k0 = 0; k0 < K; k0 += 32) {
    {   // stage X tile (64 rows x 32 k), transposed into xs[kk][r]
      int r  = tid >> 2;
      int kb = (tid & 3) * 8;
      const float* src = X + r * ldx + k0 + kb;
      float4 v0 = *(const float4*)(src);
      float4 v1 = *(const float4*)(src + 4);
      xs[kb + 0][r] = v0.x; xs[kb + 1][r] = v0.y; xs[kb + 2][r] = v0.z; xs[kb + 3][r] = v0.w;
      xs[kb + 4][r] = v1.x; xs[kb + 5][r] = v1.y; xs[kb + 6][r] = v1.z; xs[kb + 7][r] = v1.w;
    }
    {   // stage W tile transposed: wst[c][kk], 16 cols x 32 kk
      int kk = tid >> 4;
      int c  = tid & 15;
      wst[c][kk]      = W[(size_t)(k0 + kk)      * G4_ + c0 + c];
      wst[c][kk + 16] = W[(size_t)(k0 + kk + 16) * G4_ + c0 + c];
    }
    __syncthreads();
    #pragma unroll
    for (int kq = 0; kq < 8; ++kq) {
      float4 wv = *(const float4*)&wst[tc][kq * 4];
      float4 x0 = *(const float4*)&xs[kq * 4 + 0][tr * 4];
      acc0 = fmaf(x0.x, wv.x, acc0); acc1 = fmaf(x0.y, wv.x, acc1);
      acc2 = fmaf(x0.z, wv.x, acc2); acc3 = fmaf(x0.w, wv.x, acc3);
      float4 x1 = *(const float4*)&xs[kq * 4 + 1][tr * 4];
      acc0 = fmaf(x1.x, wv.y, acc0); acc1 = fmaf(x1.y, wv.y, acc1);
      acc2 = fmaf(x1.z, wv.y, acc2); acc3 = fmaf(x1.w, wv.y, acc3);
      float4 x2 = *(const float4*)&xs[kq * 4 + 2][tr * 4];
      acc0 = fmaf(x2.x, wv.z, acc0); acc1 = fmaf(x2.y, wv.z, acc1);
      acc2 = fmaf(x2.z, wv.z, acc2); acc3 = fmaf(x2.w, wv.z, acc3);
      float4 x3 = *(const float4*)&xs[kq * 4 + 3][tr * 4];
      acc0 = fmaf(x3.x, wv.w, acc0); acc1 = fmaf(x3.y, wv.w, acc1);
      acc2 = fmaf(x3.z, wv.w, acc2); acc3 = fmaf(x3.w, wv.w, acc3);
    }
    __syncthreads();
  }

  int c = c0 + tc;
  float bb = b1[c] + b2[c];
  int r = tr * 4;
  G[(size_t)(r + 0) * G4_ + c] = acc0 + bb;
  G[(size_t)(r + 1) * G4_ + c] = acc1 + bb;
  G[(size_t)(r + 2) * G4_ + c] = acc2 + bb;
  G[(size_t)(r + 3) * G4_ + c] = acc3 + bb;
}

// ---------------------------------------------------------------------------
// LSTM activation (zero initial state, f-gate dead):
// h = sigmoid(o) * tanh( sigmoid(i) * tanh(g) )
// grid 64 x 256
// ---------------------------------------------------------------------------
__global__ void lstm_act_kernel(const float* __restrict__ G, float* __restrict__ H) {
  int n = blockIdx.x;
  int tid = threadIdx.x;
  for (int j = tid; j < H_; j += 256) {
    float gi = G[(size_t)n * G4_ + j];
    float gg = G[(size_t)n * G4_ + 2048 + j];
    float go = G[(size_t)n * G4_ + 3072 + j];
    float cc = sigmoidf_(gi) * tanhf(gg);
    H[n * H_ + j] = sigmoidf_(go) * tanhf(cc);
  }
}

// ---------------------------------------------------------------------------
// K6: fused h2 activation + output GEMM: out[n, c] = dec @ w_out + b_out,
// dec = [h2 (1024) | context (512)].  grid 64 x 192 threads.
// ---------------------------------------------------------------------------
__global__ void out_kernel(const float* __restrict__ G1,
                           const float* __restrict__ xbuf,
                           const float* __restrict__ w_out,
                           const float* __restrict__ b_out,
                           float* __restrict__ out) {
  int n = blockIdx.x;
  int tid = threadIdx.x;
  __shared__ float dl[1536];
  for (int j = tid; j < H_; j += 192) {
    float gi = G1[(size_t)n * G4_ + j];
    float gg = G1[(size_t)n * G4_ + 2048 + j];
    float go = G1[(size_t)n * G4_ + 3072 + j];
    dl[j] = sigmoidf_(go) * tanhf(sigmoidf_(gi) * tanhf(gg));
  }
  for (int e = tid; e < E_; e += 192) dl[1024 + e] = xbuf[n * 832 + 256 + e];
  __syncthreads();
  if (tid < 160) {
    float acc = b_out[tid];
    #pragma unroll 4
    for (int k = 0; k < 1536; ++k) acc = fmaf(dl[k], w_out[k * 160 + tid], acc);
    out[n * 160 + tid] = acc;
  }
}

// ---------------------------------------------------------------------------
extern "C" void kernel_launch(void* const* d_in, const int* in_sizes, int n_in,
                              void* d_out, int out_size, void* d_ws, size_t ws_size,
                              hipStream_t stream) {
  const float* input_enc = (const float*)d_in[0];
  const float* input_dec = (const float*)d_in[1];
  const float* spkr_vec  = (const float*)d_in[2];
  const int*   lengths   = (const int*)  d_in[3];
  const float* w_enc     = (const float*)d_in[4];
  const float* b_enc     = (const float*)d_in[5];
  const float* w_spkr    = (const float*)d_in[6];
  const float* conv_w    = (const float*)d_in[7];
  const float* w_proj    = (const float*)d_in[8];
  // d_in[9]  b_proj: constant across t -> cancels in softmax
  const float* w_p1      = (const float*)d_in[10];
  const float* b_p1      = (const float*)d_in[11];
  const float* w_p2      = (const float*)d_in[12];
  const float* b_p2      = (const float*)d_in[13];
  const float* w_ih0     = (const float*)d_in[14];
  // d_in[15] w_hh0: dead
  const float* b_ih0     = (const float*)d_in[16];
  const float* b_hh0     = (const float*)d_in[17];
  const float* w_ih1     = (const float*)d_in[18];
  // d_in[19] w_hh1: dead
  const float* b_ih1     = (const float*)d_in[20];
  const float* b_hh1     = (const float*)d_in[21];
  const float* w_out     = (const float*)d_in[22];
  const float* b_out     = (const float*)d_in[23];

  float* ws    = (float*)d_ws;
  float* part  = ws;            // 64*10*4   = 2560 floats
  float* xbuf  = ws + 4096;     // 64*832    = 53248
  float* gates = ws + 65536;    // 64*4096   = 262144
  float* h1    = ws + 327680;   // 64*1024   = 65536
  float* out   = (float*)d_out; // 64*2*80   = 10240

  hipLaunchKernelGGL(logits_kernel, dim3(64, 4), dim3(256), 0, stream,
                     input_enc, spkr_vec, w_enc, b_enc, w_spkr, conv_w, w_proj, part);
  hipLaunchKernelGGL(ctx_prenet_kernel, dim3(64), dim3(256), 0, stream,
                     input_enc, input_dec, spkr_vec, lengths, part,
                     w_p1, b_p1, w_p2, b_p2, xbuf);
  hipLaunchKernelGGL(gemm_gates_kernel, dim3(192), dim3(256), 0, stream,
                     xbuf, 832, 832, w_ih0, b_ih0, b_hh0, gates);
  hipLaunchKernelGGL(lstm_act_kernel, dim3(64), dim3(256), 0, stream, gates, h1);
  hipLaunchKernelGGL(gemm_gates_kernel, dim3(192), dim3(256), 0, stream,
                     h1, 1024, 1024, w_ih1, b_ih1, b_hh1, gates);
  hipLaunchKernelGGL(out_kernel, dim3(64), dim3(192), 0, stream,
                     gates, xbuf, w_out, b_out, out);
}

// Round 2
// 107.356 us; speedup vs baseline: 3.0492x; 3.0492x over previous
//
#include <hip/hip_runtime.h>
#include <hip/hip_bf16.h>
#include <math.h>

// Problem constants
#define N_   64
#define T_   1000
#define E_   512
#define A_   256
#define O_   80
#define S_   64
#define H_   1024
#define G4_  4096
#define KC_  31   // conv kernel size, K//2 = 15

__device__ __forceinline__ float sigmoidf_(float x) { return 1.f / (1.f + __expf(-x)); }
__device__ __forceinline__ float softsignf_(float x) { return x / (1.f + fabsf(x)); }

// ---------------------------------------------------------------------------
// K1a: attention logits. grid (64 n, 4 aq) x 512 threads (8 waves).
// Lane al = local a (64 per block); wave kw owns k-chunk [kw*64, kw*64+64).
// Each w_enc load feeds 10 FMAs (one per timestep) -> high ILP; 8 waves give
// TLP. Partials reduced via LDS; epilogue computes softsign/tanh and a
// 64-lane shuffle reduce -> part[(n*10+t)*4 + aq].
// ---------------------------------------------------------------------------
__global__ __launch_bounds__(512) void logits_kernel(
    const float* __restrict__ enc,
    const float* __restrict__ spkr,
    const float* __restrict__ w_enc,
    const float* __restrict__ b_enc,
    const float* __restrict__ w_spkr,
    const float* __restrict__ conv_w,
    const float* __restrict__ w_proj,
    float* __restrict__ part) {
  int n  = blockIdx.x;
  int aq = blockIdx.y;
  int tid = threadIdx.x;
  int al = tid & 63;
  int kw = tid >> 6;        // 0..7
  int a  = aq * 64 + al;

  __shared__ float smem[5120];   // er[10][512], later reused as part_l[8][10][64]
  __shared__ float sp[S_];
  __shared__ float bsl[S_];

  if (tid < S_) sp[tid] = spkr[n * S_ + tid];
  // stage enc rows t=0..9 as float4 (1280 float4s / 512 threads)
  {
    const float4* src = (const float4*)(enc + (size_t)n * T_ * E_);
    float4* dst = (float4*)smem;
    for (int i = tid; i < 1280; i += 512) dst[i] = src[i];
  }
  __syncthreads();

  // bias_spkr (per a), by first 64 threads
  if (tid < S_) {
    float b = 0.f;
    #pragma unroll 8
    for (int s = 0; s < S_; ++s) b += sp[s] * w_spkr[s * A_ + aq * 64 + tid];
    bsl[tid] = softsignf_(b);
  }

  // main loop: this wave's 64-k chunk, 10 t's per load
  float acc[10];
  #pragma unroll
  for (int t = 0; t < 10; ++t) acc[t] = 0.f;
  const int kbase = kw * 64;
  const float* wcol = w_enc + a;
  #pragma unroll 8
  for (int k = 0; k < 64; ++k) {
    float we = wcol[(size_t)(kbase + k) * A_];
    #pragma unroll
    for (int t = 0; t < 10; ++t)
      acc[t] = fmaf(smem[t * E_ + kbase + k], we, acc[t]);
  }

  __syncthreads();   // done reading er; reuse smem for partials
  #pragma unroll
  for (int t = 0; t < 10; ++t) smem[(kw * 10 + t) * 64 + al] = acc[t];
  __syncthreads();

  // epilogue: (t, al) pairs; 512 threads cover t=0..7 then t=8..9
  #pragma unroll
  for (int tb = 0; tb < 10; tb += 8) {
    int t = tb + kw;
    if (t < 10 && (tb == 0 || kw < 2)) {
      float p = b_enc[a];
      #pragma unroll
      for (int w = 0; w < 8; ++w) p += smem[(w * 10 + t) * 64 + al];
      float e = softsignf_(p) + bsl[al] + conv_w[a * KC_ + (15 - t)];
      float l = tanhf(e) * w_proj[a];
      #pragma unroll
      for (int off = 32; off > 0; off >>= 1) l += __shfl_down(l, off);
      if (al == 0) part[(n * 10 + t) * 4 + aq] = l;
    }
  }
}

// ---------------------------------------------------------------------------
// K1b: softmax (10 wide) + context + prenet + assemble x = [pre2|ctx|spkr].
// grid 64 blocks x 512 threads.
// ---------------------------------------------------------------------------
__global__ __launch_bounds__(512) void ctx_prenet_kernel(
    const float* __restrict__ enc,
    const float* __restrict__ dec_in,
    const float* __restrict__ spkr,
    const int*   __restrict__ lengths,
    const float* __restrict__ part,
    const float* __restrict__ w_p1,
    const float* __restrict__ b_p1,
    const float* __restrict__ w_p2,
    const float* __restrict__ b_p2,
    float* __restrict__ xbuf) {
  int n = blockIdx.x;
  int tid = threadIdx.x;
  __shared__ float att[10];
  __shared__ float incat[O_ + S_];   // 144
  __shared__ float pre1[512];
  __shared__ float pp2[2][A_];

  if (tid < S_) {
    float s = spkr[n * S_ + tid];
    incat[O_ + tid] = s;
    xbuf[n * 832 + 768 + tid] = s;
  }
  if (tid < O_) incat[tid] = dec_in[n * O_ + tid];
  if (tid == 0) {
    int lim = lengths[n] - 1; if (lim < 0) lim = 0;
    int tmax = lim < 9 ? lim : 9;
    float lg[10];
    float m = -1e30f;
    for (int t = 0; t <= tmax; ++t) {
      const float* p = &part[(n * 10 + t) * 4];
      lg[t] = p[0] + p[1] + p[2] + p[3];
      m = fmaxf(m, lg[t]);
    }
    float ssum = 0.f;
    for (int t = 0; t <= tmax; ++t) { float w = __expf(lg[t] - m); att[t] = w; ssum += w; }
    float inv = 1.f / fmaxf(ssum, 1e-12f);
    for (int t = 0; t <= tmax; ++t) att[t] *= inv;
    for (int t = tmax + 1; t < 10; ++t) att[t] = 0.f;
  }
  __syncthreads();

  // context -> xbuf[n][256 + e]   (512 threads, 1 element each)
  {
    float c = 0.f;
    #pragma unroll
    for (int t = 0; t < 10; ++t)
      c = fmaf(att[t], enc[(size_t)n * T_ * E_ + t * E_ + tid], c);
    xbuf[n * 832 + 256 + tid] = c;
  }

  // pre1 = relu(incat @ w_p1 + b_p1)   (144 x 512), 1 col/thread
  {
    float v = b_p1[tid];
    #pragma unroll 8
    for (int k = 0; k < O_ + S_; ++k) v = fmaf(incat[k], w_p1[k * 512 + tid], v);
    pre1[tid] = fmaxf(v, 0.f);
  }
  __syncthreads();

  // pre2 = relu(pre1 @ w_p2 + b_p2)    (512 x 256), 2-way K split
  {
    int c  = tid & 255;
    int kh = tid >> 8;
    float v = 0.f;
    #pragma unroll 8
    for (int k = kh * 256; k < kh * 256 + 256; ++k)
      v = fmaf(pre1[k], w_p2[k * A_ + c], v);
    pp2[kh][c] = v;
  }
  __syncthreads();
  if (tid < A_) {
    float v = b_p2[tid] + pp2[0][tid] + pp2[1][tid];
    xbuf[n * 832 + tid] = fmaxf(v, 0.f);
  }
}

// ---------------------------------------------------------------------------
// GEMM: G[64 x 4096] = X[64 x K] @ W[K x 4096] + b1 + b2, only i/g/o columns.
// grid 192 blocks (16-col tiles over the 3072 live cols) x 256 threads.
// ---------------------------------------------------------------------------
__global__ void gemm_gates_kernel(const float* __restrict__ X, int ldx, int K,
                                  const float* __restrict__ W,
                                  const float* __restrict__ b1,
                                  const float* __restrict__ b2,
                                  float* __restrict__ G) {
  int bt = blockIdx.x;
  int c0 = bt * 16; if (c0 >= 1024) c0 += 1024;   // skip dead f-gate columns
  int tid = threadIdx.x;
  int tr = tid >> 4;     // 0..15
  int tc = tid & 15;     // 0..15

  __shared__ __align__(16) float xs[32][64];
  __shared__ __align__(16) float wst[16][36];     // padded stride kills bank conflicts

  float acc0 = 0.f, acc1 = 0.f, acc2 = 0.f, acc3 = 0.f;

  for (int k0 = 0; k0 < K; k0 += 32) {
    {   // stage X tile (64 rows x 32 k), transposed into xs[kk][r]
      int r  = tid >> 2;
      int kb = (tid & 3) * 8;
      const float* src = X + r * ldx + k0 + kb;
      float4 v0 = *(const float4*)(src);
      float4 v1 = *(const float4*)(src + 4);
      xs[kb + 0][r] = v0.x; xs[kb + 1][r] = v0.y; xs[kb + 2][r] = v0.z; xs[kb + 3][r] = v0.w;
      xs[kb + 4][r] = v1.x; xs[kb + 5][r] = v1.y; xs[kb + 6][r] = v1.z; xs[kb + 7][r] = v1.w;
    }
    {   // stage W tile transposed: wst[c][kk], 16 cols x 32 kk
      int kk = tid >> 4;
      int c  = tid & 15;
      wst[c][kk]      = W[(size_t)(k0 + kk)      * G4_ + c0 + c];
      wst[c][kk + 16] = W[(size_t)(k0 + kk + 16) * G4_ + c0 + c];
    }
    __syncthreads();
    #pragma unroll
    for (int kq = 0; kq < 8; ++kq) {
      float4 wv = *(const float4*)&wst[tc][kq * 4];
      float4 x0 = *(const float4*)&xs[kq * 4 + 0][tr * 4];
      acc0 = fmaf(x0.x, wv.x, acc0); acc1 = fmaf(x0.y, wv.x, acc1);
      acc2 = fmaf(x0.z, wv.x, acc2); acc3 = fmaf(x0.w, wv.x, acc3);
      float4 x1 = *(const float4*)&xs[kq * 4 + 1][tr * 4];
      acc0 = fmaf(x1.x, wv.y, acc0); acc1 = fmaf(x1.y, wv.y, acc1);
      acc2 = fmaf(x1.z, wv.y, acc2); acc3 = fmaf(x1.w, wv.y, acc3);
      float4 x2 = *(const float4*)&xs[kq * 4 + 2][tr * 4];
      acc0 = fmaf(x2.x, wv.z, acc0); acc1 = fmaf(x2.y, wv.z, acc1);
      acc2 = fmaf(x2.z, wv.z, acc2); acc3 = fmaf(x2.w, wv.z, acc3);
      float4 x3 = *(const float4*)&xs[kq * 4 + 3][tr * 4];
      acc0 = fmaf(x3.x, wv.w, acc0); acc1 = fmaf(x3.y, wv.w, acc1);
      acc2 = fmaf(x3.z, wv.w, acc2); acc3 = fmaf(x3.w, wv.w, acc3);
    }
    __syncthreads();
  }

  int c = c0 + tc;
  float bb = b1[c] + b2[c];
  int r = tr * 4;
  G[(size_t)(r + 0) * G4_ + c] = acc0 + bb;
  G[(size_t)(r + 1) * G4_ + c] = acc1 + bb;
  G[(size_t)(r + 2) * G4_ + c] = acc2 + bb;
  G[(size_t)(r + 3) * G4_ + c] = acc3 + bb;
}

// ---------------------------------------------------------------------------
// LSTM activation (zero initial state, f-gate dead):
// h = sigmoid(o) * tanh( sigmoid(i) * tanh(g) )
// ---------------------------------------------------------------------------
__global__ void lstm_act_kernel(const float* __restrict__ G, float* __restrict__ H) {
  int n = blockIdx.x;
  int tid = threadIdx.x;
  for (int j = tid; j < H_; j += 256) {
    float gi = G[(size_t)n * G4_ + j];
    float gg = G[(size_t)n * G4_ + 2048 + j];
    float go = G[(size_t)n * G4_ + 3072 + j];
    float cc = sigmoidf_(gi) * tanhf(gg);
    H[n * H_ + j] = sigmoidf_(go) * tanhf(cc);
  }
}

// ---------------------------------------------------------------------------
// K6: fused h2 activation + output GEMM. grid 64 x 1024 threads.
// dec = [h2 (1024) | context (512)], out[n,c] = dec @ w_out + b_out.
// 6-way K split (256 k each) + LDS reduce.
// ---------------------------------------------------------------------------
__global__ __launch_bounds__(1024) void out_kernel(
    const float* __restrict__ G1,
    const float* __restrict__ xbuf,
    const float* __restrict__ w_out,
    const float* __restrict__ b_out,
    float* __restrict__ out) {
  int n = blockIdx.x;
  int tid = threadIdx.x;
  __shared__ float dl[1536];
  __shared__ float pp[6][160];
  {   // h2 activation, 1 element/thread
    float gi = G1[(size_t)n * G4_ + tid];
    float gg = G1[(size_t)n * G4_ + 2048 + tid];
    float go = G1[(size_t)n * G4_ + 3072 + tid];
    dl[tid] = sigmoidf_(go) * tanhf(sigmoidf_(gi) * tanhf(gg));
  }
  if (tid < E_) dl[1024 + tid] = xbuf[n * 832 + 256 + tid];
  __syncthreads();
  if (tid < 960) {
    int c  = tid % 160;
    int kq = tid / 160;
    float acc = 0.f;
    const float* wp = w_out + (size_t)(kq * 256) * 160 + c;
    const float* dp = dl + kq * 256;
    #pragma unroll 8
    for (int k = 0; k < 256; ++k) acc = fmaf(dp[k], wp[(size_t)k * 160], acc);
    pp[kq][c] = acc;
  }
  __syncthreads();
  if (tid < 160) {
    float r = b_out[tid] + pp[0][tid] + pp[1][tid] + pp[2][tid]
            + pp[3][tid] + pp[4][tid] + pp[5][tid];
    out[n * 160 + tid] = r;
  }
}

// ---------------------------------------------------------------------------
extern "C" void kernel_launch(void* const* d_in, const int* in_sizes, int n_in,
                              void* d_out, int out_size, void* d_ws, size_t ws_size,
                              hipStream_t stream) {
  const float* input_enc = (const float*)d_in[0];
  const float* input_dec = (const float*)d_in[1];
  const float* spkr_vec  = (const float*)d_in[2];
  const int*   lengths   = (const int*)  d_in[3];
  const float* w_enc     = (const float*)d_in[4];
  const float* b_enc     = (const float*)d_in[5];
  const float* w_spkr    = (const float*)d_in[6];
  const float* conv_w    = (const float*)d_in[7];
  const float* w_proj    = (const float*)d_in[8];
  // d_in[9]  b_proj: constant across t -> cancels in softmax
  const float* w_p1      = (const float*)d_in[10];
  const float* b_p1      = (const float*)d_in[11];
  const float* w_p2      = (const float*)d_in[12];
  const float* b_p2      = (const float*)d_in[13];
  const float* w_ih0     = (const float*)d_in[14];
  // d_in[15] w_hh0: dead
  const float* b_ih0     = (const float*)d_in[16];
  const float* b_hh0     = (const float*)d_in[17];
  const float* w_ih1     = (const float*)d_in[18];
  // d_in[19] w_hh1: dead
  const float* b_ih1     = (const float*)d_in[20];
  const float* b_hh1     = (const float*)d_in[21];
  const float* w_out     = (const float*)d_in[22];
  const float* b_out     = (const float*)d_in[23];

  float* ws    = (float*)d_ws;
  float* part  = ws;            // 64*10*4   = 2560 floats
  float* xbuf  = ws + 4096;     // 64*832    = 53248
  float* gates = ws + 65536;    // 64*4096   = 262144
  float* h1    = ws + 327680;   // 64*1024   = 65536
  float* out   = (float*)d_out; // 64*2*80   = 10240

  hipLaunchKernelGGL(logits_kernel, dim3(64, 4), dim3(512), 0, stream,
                     input_enc, spkr_vec, w_enc, b_enc, w_spkr, conv_w, w_proj, part);
  hipLaunchKernelGGL(ctx_prenet_kernel, dim3(64), dim3(512), 0, stream,
                     input_enc, input_dec, spkr_vec, lengths, part,
                     w_p1, b_p1, w_p2, b_p2, xbuf);
  hipLaunchKernelGGL(gemm_gates_kernel, dim3(192), dim3(256), 0, stream,
                     xbuf, 832, 832, w_ih0, b_ih0, b_hh0, gates);
  hipLaunchKernelGGL(lstm_act_kernel, dim3(64), dim3(256), 0, stream, gates, h1);
  hipLaunchKernelGGL(gemm_gates_kernel, dim3(192), dim3(256), 0, stream,
                     h1, 1024, 1024, w_ih1, b_ih1, b_hh1, gates);
  hipLaunchKernelGGL(out_kernel, dim3(64), dim3(1024), 0, stream,
                     gates, xbuf, w_out, b_out, out);
}

// Round 3
// 98.801 us; speedup vs baseline: 3.3132x; 1.0866x over previous
//
#include <hip/hip_runtime.h>
#include <hip/hip_bf16.h>
#include <math.h>

// Problem constants
#define N_   64
#define T_   1000
#define E_   512
#define A_   256
#define O_   80
#define S_   64
#define H_   1024
#define G4_  4096
#define KC_  31   // conv kernel size, K//2 = 15

__device__ __forceinline__ float sigmoidf_(float x) { return 1.f / (1.f + __expf(-x)); }
__device__ __forceinline__ float softsignf_(float x) { return x / (1.f + fabsf(x)); }

// ---------------------------------------------------------------------------
// K1a: attention logits. grid (64 n, 4 aq) x 512 threads (8 waves).
// Lane al = local a (64 per block); wave kw owns k-chunk [kw*64, kw*64+64).
// Each w_enc load feeds 10 FMAs (one per timestep) -> high ILP.
// ---------------------------------------------------------------------------
__global__ __launch_bounds__(512) void logits_kernel(
    const float* __restrict__ enc,
    const float* __restrict__ spkr,
    const float* __restrict__ w_enc,
    const float* __restrict__ b_enc,
    const float* __restrict__ w_spkr,
    const float* __restrict__ conv_w,
    const float* __restrict__ w_proj,
    float* __restrict__ part) {
  int n  = blockIdx.x;
  int aq = blockIdx.y;
  int tid = threadIdx.x;
  int al = tid & 63;
  int kw = tid >> 6;        // 0..7
  int a  = aq * 64 + al;

  __shared__ float smem[5120];   // er[10][512], later reused as part_l[8][10][64]
  __shared__ float sp[S_];
  __shared__ float bsl[S_];

  if (tid < S_) sp[tid] = spkr[n * S_ + tid];
  // stage enc rows t=0..9 as float4 (1280 float4s / 512 threads)
  {
    const float4* src = (const float4*)(enc + (size_t)n * T_ * E_);
    float4* dst = (float4*)smem;
    for (int i = tid; i < 1280; i += 512) dst[i] = src[i];
  }
  __syncthreads();

  // bias_spkr (per a), by first 64 threads
  if (tid < S_) {
    float b = 0.f;
    #pragma unroll 8
    for (int s = 0; s < S_; ++s) b += sp[s] * w_spkr[s * A_ + aq * 64 + tid];
    bsl[tid] = softsignf_(b);
  }

  // main loop: this wave's 64-k chunk, 10 t's per load
  float acc[10];
  #pragma unroll
  for (int t = 0; t < 10; ++t) acc[t] = 0.f;
  const int kbase = kw * 64;
  const float* wcol = w_enc + a;
  #pragma unroll 8
  for (int k = 0; k < 64; ++k) {
    float we = wcol[(size_t)(kbase + k) * A_];
    #pragma unroll
    for (int t = 0; t < 10; ++t)
      acc[t] = fmaf(smem[t * E_ + kbase + k], we, acc[t]);
  }

  __syncthreads();   // done reading er; reuse smem for partials
  #pragma unroll
  for (int t = 0; t < 10; ++t) smem[(kw * 10 + t) * 64 + al] = acc[t];
  __syncthreads();

  // epilogue: (t, al) pairs; 512 threads cover t=0..7 then t=8..9
  #pragma unroll
  for (int tb = 0; tb < 10; tb += 8) {
    int t = tb + kw;
    if (t < 10 && (tb == 0 || kw < 2)) {
      float p = b_enc[a];
      #pragma unroll
      for (int w = 0; w < 8; ++w) p += smem[(w * 10 + t) * 64 + al];
      float e = softsignf_(p) + bsl[al] + conv_w[a * KC_ + (15 - t)];
      float l = tanhf(e) * w_proj[a];
      #pragma unroll
      for (int off = 32; off > 0; off >>= 1) l += __shfl_down(l, off);
      if (al == 0) part[(n * 10 + t) * 4 + aq] = l;
    }
  }
}

// ---------------------------------------------------------------------------
// K1b: softmax (10 wide) + context + prenet + assemble x = [pre2|ctx|spkr].
// grid 64 blocks x 512 threads.
// ---------------------------------------------------------------------------
__global__ __launch_bounds__(512) void ctx_prenet_kernel(
    const float* __restrict__ enc,
    const float* __restrict__ dec_in,
    const float* __restrict__ spkr,
    const int*   __restrict__ lengths,
    const float* __restrict__ part,
    const float* __restrict__ w_p1,
    const float* __restrict__ b_p1,
    const float* __restrict__ w_p2,
    const float* __restrict__ b_p2,
    float* __restrict__ xbuf) {
  int n = blockIdx.x;
  int tid = threadIdx.x;
  __shared__ float att[10];
  __shared__ float incat[O_ + S_];   // 144
  __shared__ float pre1[512];
  __shared__ float pp2[2][A_];

  if (tid < S_) {
    float s = spkr[n * S_ + tid];
    incat[O_ + tid] = s;
    xbuf[n * 832 + 768 + tid] = s;
  }
  if (tid < O_) incat[tid] = dec_in[n * O_ + tid];
  if (tid == 0) {
    int lim = lengths[n] - 1; if (lim < 0) lim = 0;
    int tmax = lim < 9 ? lim : 9;
    float lg[10];
    float m = -1e30f;
    for (int t = 0; t <= tmax; ++t) {
      const float* p = &part[(n * 10 + t) * 4];
      lg[t] = p[0] + p[1] + p[2] + p[3];
      m = fmaxf(m, lg[t]);
    }
    float ssum = 0.f;
    for (int t = 0; t <= tmax; ++t) { float w = __expf(lg[t] - m); att[t] = w; ssum += w; }
    float inv = 1.f / fmaxf(ssum, 1e-12f);
    for (int t = 0; t <= tmax; ++t) att[t] *= inv;
    for (int t = tmax + 1; t < 10; ++t) att[t] = 0.f;
  }
  __syncthreads();

  // context -> xbuf[n][256 + e]   (512 threads, 1 element each)
  {
    float c = 0.f;
    #pragma unroll
    for (int t = 0; t < 10; ++t)
      c = fmaf(att[t], enc[(size_t)n * T_ * E_ + t * E_ + tid], c);
    xbuf[n * 832 + 256 + tid] = c;
  }

  // pre1 = relu(incat @ w_p1 + b_p1)   (144 x 512), 1 col/thread
  {
    float v = b_p1[tid];
    #pragma unroll 8
    for (int k = 0; k < O_ + S_; ++k) v = fmaf(incat[k], w_p1[k * 512 + tid], v);
    pre1[tid] = fmaxf(v, 0.f);
  }
  __syncthreads();

  // pre2 = relu(pre1 @ w_p2 + b_p2)    (512 x 256), 2-way K split
  {
    int c  = tid & 255;
    int kh = tid >> 8;
    float v = 0.f;
    #pragma unroll 8
    for (int k = kh * 256; k < kh * 256 + 256; ++k)
      v = fmaf(pre1[k], w_p2[k * A_ + c], v);
    pp2[kh][c] = v;
  }
  __syncthreads();
  if (tid < A_) {
    float v = b_p2[tid] + pp2[0][tid] + pp2[1][tid];
    xbuf[n * 832 + tid] = fmaxf(v, 0.f);
  }
}

// ---------------------------------------------------------------------------
// GEMM: G[64 x 4096] = X[64 x K] @ W[K x 4096] + b1 + b2, only i/g/o columns.
// grid 192 blocks (16-col tiles over the 3072 live cols) x 512 threads.
// In-block K-split (kh = tid>>8 owns half of K), LDS reduce at the end.
// W loaded straight to registers (wave-coalesced, L1-deduped across waves).
// X chunk staged to LDS, software-pipelined: load next (global->reg) before
// compute, ds_write after compute, one barrier per chunk.
// ---------------------------------------------------------------------------
__global__ __launch_bounds__(512) void gemm_gates_kernel(
    const float* __restrict__ X, int ldx, int K,
    const float* __restrict__ W,
    const float* __restrict__ b1,
    const float* __restrict__ b2,
    float* __restrict__ G) {
  int bt = blockIdx.x;
  int c0 = bt * 16; if (c0 >= 1024) c0 += 1024;   // skip dead f-gate columns
  int tid = threadIdx.x;
  int kh  = tid >> 8;        // K half
  int lt  = tid & 255;
  int tr  = lt >> 4;         // 0..15 row group
  int tc  = lt & 15;         // 0..15 col
  int c   = c0 + tc;
  int Kh  = K >> 1;          // 416 / 512 (both multiples of 32)
  int kbeg = kh * Kh;
  int NC  = Kh >> 5;

  // staging mapping: lane -> row, quarter -> k-octet (writes 2-way-alias free)
  int rr  = lt & 63;
  int kb8 = (lt >> 6) << 3;

  __shared__ float xs[2][2][32][64];   // [kh][buf][kk][r], 32 KB
  __shared__ float red[16][16][4];     // 4 KB

  const float* xsrc = X + (size_t)rr * ldx + kbeg + kb8;

  float4 xv0 = ((const float4*)xsrc)[0];
  float4 xv1 = ((const float4*)(xsrc + 4))[0];
  {
    float* d = &xs[kh][0][kb8][rr];
    d[0]   = xv0.x; d[64]  = xv0.y; d[128] = xv0.z; d[192] = xv0.w;
    d[256] = xv1.x; d[320] = xv1.y; d[384] = xv1.z; d[448] = xv1.w;
  }
  __syncthreads();

  float acc0 = 0.f, acc1 = 0.f, acc2 = 0.f, acc3 = 0.f;
  for (int ch = 0; ch < NC; ++ch) {
    int buf = ch & 1;
    // W for current chunk -> registers (16 consecutive floats per wave-row,
    // 4 tr-groups read identical addresses -> coalesced + L1)
    float wreg[32];
    const float* wp = W + (size_t)(kbeg + ch * 32) * G4_ + c;
    #pragma unroll
    for (int kk = 0; kk < 32; ++kk) wreg[kk] = wp[(size_t)kk * G4_];
    // issue next chunk's X loads early (latency hides under compute)
    bool more = (ch + 1 < NC);
    if (more) {
      const float* s = xsrc + (ch + 1) * 32;
      xv0 = ((const float4*)s)[0];
      xv1 = ((const float4*)(s + 4))[0];
    }
    // compute: 32 x (16-way-broadcast b128 + 4 FMA)
    const float* xb = &xs[kh][buf][0][tr * 4];
    #pragma unroll
    for (int kk = 0; kk < 32; ++kk) {
      float4 xv = *(const float4*)(xb + kk * 64);
      acc0 = fmaf(xv.x, wreg[kk], acc0);
      acc1 = fmaf(xv.y, wreg[kk], acc1);
      acc2 = fmaf(xv.z, wreg[kk], acc2);
      acc3 = fmaf(xv.w, wreg[kk], acc3);
    }
    if (more) {
      float* d = &xs[kh][buf ^ 1][kb8][rr];
      d[0]   = xv0.x; d[64]  = xv0.y; d[128] = xv0.z; d[192] = xv0.w;
      d[256] = xv1.x; d[320] = xv1.y; d[384] = xv1.z; d[448] = xv1.w;
    }
    __syncthreads();
  }

  if (kh == 1) {
    red[tr][tc][0] = acc0; red[tr][tc][1] = acc1;
    red[tr][tc][2] = acc2; red[tr][tc][3] = acc3;
  }
  __syncthreads();
  if (kh == 0) {
    float bb = b1[c] + b2[c];
    int r = tr * 4;
    G[(size_t)(r + 0) * G4_ + c] = acc0 + red[tr][tc][0] + bb;
    G[(size_t)(r + 1) * G4_ + c] = acc1 + red[tr][tc][1] + bb;
    G[(size_t)(r + 2) * G4_ + c] = acc2 + red[tr][tc][2] + bb;
    G[(size_t)(r + 3) * G4_ + c] = acc3 + red[tr][tc][3] + bb;
  }
}

// ---------------------------------------------------------------------------
// LSTM activation (zero initial state, f-gate dead):
// h = sigmoid(o) * tanh( sigmoid(i) * tanh(g) )
// grid 256 x 256, 1 element/thread
// ---------------------------------------------------------------------------
__global__ void lstm_act_kernel(const float* __restrict__ G, float* __restrict__ H) {
  int idx = blockIdx.x * 256 + threadIdx.x;   // 65536 = 64 n x 1024 j
  int n = idx >> 10;
  int j = idx & 1023;
  float gi = G[(size_t)n * G4_ + j];
  float gg = G[(size_t)n * G4_ + 2048 + j];
  float go = G[(size_t)n * G4_ + 3072 + j];
  float cc = sigmoidf_(gi) * tanhf(gg);
  H[n * H_ + j] = sigmoidf_(go) * tanhf(cc);
}

// ---------------------------------------------------------------------------
// K6: fused h2 activation + output GEMM. grid 64 x 1024 threads.
// dec = [h2 (1024) | context (512)], out[n,c] = dec @ w_out + b_out.
// ---------------------------------------------------------------------------
__global__ __launch_bounds__(1024) void out_kernel(
    const float* __restrict__ G1,
    const float* __restrict__ xbuf,
    const float* __restrict__ w_out,
    const float* __restrict__ b_out,
    float* __restrict__ out) {
  int n = blockIdx.x;
  int tid = threadIdx.x;
  __shared__ float dl[1536];
  __shared__ float pp[6][160];
  {   // h2 activation, 1 element/thread
    float gi = G1[(size_t)n * G4_ + tid];
    float gg = G1[(size_t)n * G4_ + 2048 + tid];
    float go = G1[(size_t)n * G4_ + 3072 + tid];
    dl[tid] = sigmoidf_(go) * tanhf(sigmoidf_(gi) * tanhf(gg));
  }
  if (tid < E_) dl[1024 + tid] = xbuf[n * 832 + 256 + tid];
  __syncthreads();
  if (tid < 960) {
    int c  = tid % 160;
    int kq = tid / 160;
    float acc = 0.f;
    const float* wp = w_out + (size_t)(kq * 256) * 160 + c;
    const float* dp = dl + kq * 256;
    #pragma unroll 8
    for (int k = 0; k < 256; ++k) acc = fmaf(dp[k], wp[(size_t)k * 160], acc);
    pp[kq][c] = acc;
  }
  __syncthreads();
  if (tid < 160) {
    float r = b_out[tid] + pp[0][tid] + pp[1][tid] + pp[2][tid]
            + pp[3][tid] + pp[4][tid] + pp[5][tid];
    out[n * 160 + tid] = r;
  }
}

// ---------------------------------------------------------------------------
extern "C" void kernel_launch(void* const* d_in, const int* in_sizes, int n_in,
                              void* d_out, int out_size, void* d_ws, size_t ws_size,
                              hipStream_t stream) {
  const float* input_enc = (const float*)d_in[0];
  const float* input_dec = (const float*)d_in[1];
  const float* spkr_vec  = (const float*)d_in[2];
  const int*   lengths   = (const int*)  d_in[3];
  const float* w_enc     = (const float*)d_in[4];
  const float* b_enc     = (const float*)d_in[5];
  const float* w_spkr    = (const float*)d_in[6];
  const float* conv_w    = (const float*)d_in[7];
  const float* w_proj    = (const float*)d_in[8];
  // d_in[9]  b_proj: constant across t -> cancels in softmax
  const float* w_p1      = (const float*)d_in[10];
  const float* b_p1      = (const float*)d_in[11];
  const float* w_p2      = (const float*)d_in[12];
  const float* b_p2      = (const float*)d_in[13];
  const float* w_ih0     = (const float*)d_in[14];
  // d_in[15] w_hh0: dead
  const float* b_ih0     = (const float*)d_in[16];
  const float* b_hh0     = (const float*)d_in[17];
  const float* w_ih1     = (const float*)d_in[18];
  // d_in[19] w_hh1: dead
  const float* b_ih1     = (const float*)d_in[20];
  const float* b_hh1     = (const float*)d_in[21];
  const float* w_out     = (const float*)d_in[22];
  const float* b_out     = (const float*)d_in[23];

  float* ws    = (float*)d_ws;
  float* part  = ws;            // 64*10*4   = 2560 floats
  float* xbuf  = ws + 4096;     // 64*832    = 53248
  float* gates = ws + 65536;    // 64*4096   = 262144
  float* h1    = ws + 327680;   // 64*1024   = 65536
  float* out   = (float*)d_out; // 64*2*80   = 10240

  hipLaunchKernelGGL(logits_kernel, dim3(64, 4), dim3(512), 0, stream,
                     input_enc, spkr_vec, w_enc, b_enc, w_spkr, conv_w, w_proj, part);
  hipLaunchKernelGGL(ctx_prenet_kernel, dim3(64), dim3(512), 0, stream,
                     input_enc, input_dec, spkr_vec, lengths, part,
                     w_p1, b_p1, w_p2, b_p2, xbuf);
  hipLaunchKernelGGL(gemm_gates_kernel, dim3(192), dim3(512), 0, stream,
                     xbuf, 832, 832, w_ih0, b_ih0, b_hh0, gates);
  hipLaunchKernelGGL(lstm_act_kernel, dim3(256), dim3(256), 0, stream, gates, h1);
  hipLaunchKernelGGL(gemm_gates_kernel, dim3(192), dim3(512), 0, stream,
                     h1, 1024, 1024, w_ih1, b_ih1, b_hh1, gates);
  hipLaunchKernelGGL(out_kernel, dim3(64), dim3(1024), 0, stream,
                     gates, xbuf, w_out, b_out, out);
}